// Round 1
// baseline (114.797 us; speedup 1.0000x reference)
//
#include <hip/hip_runtime.h>
#include <math.h>

// Problem constants (B=2, C=4, D=H=W=128)
#define ROWS 8            // B*C independent top-k rows
#define BINS 2048         // radix bins per pass (11 bits; last pass uses 1024)
#define BPR  128          // blocks per row for full-scan passes
#define TPB  256          // threads per block

struct SelState {
    unsigned int prefix[ROWS];   // high bits of tau found so far
    unsigned int krem[ROWS];     // remaining rank within current prefix range
    unsigned int tau[ROWS];      // final exact bit pattern of n-th largest value
    double       sum_gt[ROWS];   // sum of values strictly greater than tau
};

__device__ __forceinline__ float sq_err(float x, float t) {
    float s = 1.0f / (1.0f + __expf(-x));
    float d = s - t;
    return d * d;
}

__global__ void k_init(unsigned int* __restrict__ hist, SelState* st, unsigned int n) {
    int t = threadIdx.x;
    for (int i = t; i < ROWS * BINS; i += TPB) hist[i] = 0;
    if (t < ROWS) {
        st->prefix[t] = 0u;
        st->krem[t]   = n;
        st->tau[t]    = 0u;
        st->sum_gt[t] = 0.0;
    }
}

// Histogram pass: count elements matching (bits & himask)==prefix[row], binned by (bits>>shift)&binmask
__global__ __launch_bounds__(TPB) void k_hist(const float4* __restrict__ x4,
                                              const float4* __restrict__ t4,
                                              unsigned int* __restrict__ hist,
                                              const SelState* __restrict__ st,
                                              int N, unsigned int himask, int shift,
                                              unsigned int binmask) {
    __shared__ unsigned int lh[BINS];
    const int row   = blockIdx.x / BPR;
    const int chunk = blockIdx.x % BPR;
    for (int i = threadIdx.x; i < BINS; i += TPB) lh[i] = 0u;
    __syncthreads();

    const unsigned int pref = st->prefix[row];
    const int q4 = N / (BPR * 4);                       // float4 per block
    const long long base4 = (long long)row * (N / 4) + (long long)chunk * q4;

    for (int i = threadIdx.x; i < q4; i += TPB) {
        float4 xv = x4[base4 + i];
        float4 tv = t4[base4 + i];
        const float* xp = &xv.x;
        const float* tp = &tv.x;
#pragma unroll
        for (int j = 0; j < 4; ++j) {
            float v = sq_err(xp[j], tp[j]);
            unsigned int u = __float_as_uint(v);
            if ((u & himask) == pref) {
                atomicAdd(&lh[(u >> shift) & binmask], 1u);
            }
        }
    }
    __syncthreads();
    for (int i = threadIdx.x; i < BINS; i += TPB) {
        unsigned int c = lh[i];
        if (c) atomicAdd(&hist[row * BINS + i], c);
    }
}

// Per-row: find bin where cumulative-from-top count crosses krem; update prefix/krem; zero hist.
__global__ __launch_bounds__(TPB) void k_select(unsigned int* __restrict__ hist,
                                                SelState* st, int shift, int bins, int last) {
    const int row = blockIdx.x;
    const int t   = threadIdx.x;
    const int pb  = bins / TPB;                   // bins handled per thread (8 or 4)
    unsigned int* h = &hist[row * BINS];

    const unsigned int k    = st->krem[row];      // read by everyone BEFORE any write
    const unsigned int pref = st->prefix[row];

    unsigned int local[8];
    unsigned int ts = 0;
    for (int j = 0; j < pb; ++j) { local[j] = h[t * pb + j]; ts += local[j]; }

    __shared__ unsigned int ssum[TPB];
    ssum[t] = ts;
    __syncthreads();
    // inclusive suffix scan (Hillis-Steele from the right)
    for (int off = 1; off < TPB; off <<= 1) {
        unsigned int val = (t + off < TPB) ? ssum[t + off] : 0u;
        __syncthreads();
        ssum[t] += val;
        __syncthreads();
    }
    unsigned int above = ssum[t] - ts;            // count in bins strictly above this thread's range

    for (int j = pb - 1; j >= 0; --j) {
        unsigned int c = local[j];
        if (above < k && above + c >= k) {        // exactly one (thread, j) hits this
            unsigned int b  = (unsigned int)(t * pb + j);
            unsigned int nk = k - above;
            unsigned int np = pref | (b << shift);
            st->krem[row]   = nk;
            st->prefix[row] = np;
            if (last) st->tau[row] = np;
        }
        above += c;
    }
    // zero hist for the next pass (all reads of h completed before the scan's barriers)
    for (int j = 0; j < pb; ++j) h[t * pb + j] = 0u;
}

// Sum of values strictly greater than tau, per row (double accumulation).
__global__ __launch_bounds__(TPB) void k_sum(const float4* __restrict__ x4,
                                             const float4* __restrict__ t4,
                                             SelState* st, int N) {
    const int row   = blockIdx.x / BPR;
    const int chunk = blockIdx.x % BPR;
    const unsigned int tau = st->tau[row];
    const int q4 = N / (BPR * 4);
    const long long base4 = (long long)row * (N / 4) + (long long)chunk * q4;

    double acc = 0.0;
    for (int i = threadIdx.x; i < q4; i += TPB) {
        float4 xv = x4[base4 + i];
        float4 tv = t4[base4 + i];
        const float* xp = &xv.x;
        const float* tp = &tv.x;
#pragma unroll
        for (int j = 0; j < 4; ++j) {
            float v = sq_err(xp[j], tp[j]);
            if (__float_as_uint(v) > tau) acc += (double)v;
        }
    }
    __shared__ double sh[TPB];
    sh[threadIdx.x] = acc;
    __syncthreads();
    for (int off = TPB / 2; off > 0; off >>= 1) {
        if (threadIdx.x < off) sh[threadIdx.x] += sh[threadIdx.x + off];
        __syncthreads();
    }
    if (threadIdx.x == 0) atomicAdd(&st->sum_gt[row], sh[0]);
}

__global__ void k_final(const SelState* __restrict__ st, float* __restrict__ out,
                        unsigned int n) {
    if (threadIdx.x == 0 && blockIdx.x == 0) {
        double tot = 0.0;
        for (int r = 0; r < ROWS; ++r) {
            double tauv = (double)__uint_as_float(st->tau[r]);
            tot += st->sum_gt[r] + (double)st->krem[r] * tauv;
        }
        out[0] = (float)(tot / ((double)ROWS * (double)n));
    }
}

extern "C" void kernel_launch(void* const* d_in, const int* in_sizes, int n_in,
                              void* d_out, int out_size, void* d_ws, size_t ws_size,
                              hipStream_t stream) {
    const float* x  = (const float*)d_in[0];
    const float* tg = (const float*)d_in[1];
    float* out = (float*)d_out;

    const int total = in_sizes[0];          // 16,777,216
    const int N     = total / ROWS;         // 2,097,152 voxels per (b,c) row
    unsigned int n  = (unsigned int)llround((double)N * 0.10);
    if (n < 1) n = 1;                       // 209,715

    unsigned int* hist = (unsigned int*)d_ws;                       // ROWS*BINS*4 = 64 KB
    SelState* st = (SelState*)((char*)d_ws + ROWS * BINS * sizeof(unsigned int));

    const float4* x4 = (const float4*)x;
    const float4* t4 = (const float4*)tg;

    dim3 gBig(ROWS * BPR), b(TPB);

    k_init<<<dim3(1), b, 0, stream>>>(hist, st, n);

    // pass 1: bits [31:21]
    k_hist<<<gBig, b, 0, stream>>>(x4, t4, hist, st, N, 0x00000000u, 21, 2047u);
    k_select<<<dim3(ROWS), b, 0, stream>>>(hist, st, 21, 2048, 0);
    // pass 2: bits [20:10]
    k_hist<<<gBig, b, 0, stream>>>(x4, t4, hist, st, N, 0xFFE00000u, 10, 2047u);
    k_select<<<dim3(ROWS), b, 0, stream>>>(hist, st, 10, 2048, 0);
    // pass 3: bits [9:0]
    k_hist<<<gBig, b, 0, stream>>>(x4, t4, hist, st, N, 0xFFFFFC00u, 0, 1023u);
    k_select<<<dim3(ROWS), b, 0, stream>>>(hist, st, 0, 1024, 1);

    // sum of values strictly above tau
    k_sum<<<gBig, b, 0, stream>>>(x4, t4, st, N);
    k_final<<<dim3(1), dim3(64), 0, stream>>>(st, out, n);
}